// Round 3
// baseline (279.185 us; speedup 1.0000x reference)
//
#include <hip/hip_runtime.h>
#include <hip/hip_bf16.h>

#define N 2048
#define B 16

typedef float v4f __attribute__((ext_vector_type(4)));

// Kernel 1: Asum[b,i] = sum_k |s[b,i] - s[b,k]|
// grid = (N/256, B), block = 256. Row staged in LDS, swept with float4
// broadcast reads (ds_read_b128, wave-uniform address -> no conflicts).
__global__ __launch_bounds__(256) void asum_kernel(const float* __restrict__ s,
                                                   float* __restrict__ asum) {
    const int b = blockIdx.y;
    const int i = blockIdx.x * 256 + threadIdx.x;

    __shared__ float row[N];
    const v4f* g4 = (const v4f*)(s + b * N);
    v4f* r4 = (v4f*)row;
    // 256 threads x 2 float4 = 2048 floats
    r4[threadIdx.x] = g4[threadIdx.x];
    r4[threadIdx.x + 256] = g4[threadIdx.x + 256];
    __syncthreads();

    const float si = row[i];
    const v4f* row4 = (const v4f*)row;
    float acc = 0.0f;
#pragma unroll 4
    for (int k = 0; k < N / 4; ++k) {
        v4f rv = row4[k];
        acc += fabsf(si - rv.x) + fabsf(si - rv.y) +
               fabsf(si - rv.z) + fabsf(si - rv.w);
    }
    asum[b * N + i] = acc;
}

// Kernel 2: ONE WAVE per output row (b, j). No barriers, no LDS.
// Each lane owns 32 elements as 8 float4 chunks (coalesced 16B/lane).
// out[b,j,i] = softmax_i( s[b,i]*(2047-2j) - Asum[b,i] ),  TAU = 1.
// grid = (N/4, B), block = 256 (4 waves -> 4 consecutive j per block).
__global__ __launch_bounds__(256) void softmax_rows(const float* __restrict__ s,
                                                    const float* __restrict__ asum,
                                                    float* __restrict__ out) {
    const int t = threadIdx.x;
    const int lane = t & 63;
    const int wave = t >> 6;
    const int j = blockIdx.x * 4 + wave;
    const int b = blockIdx.y;

    const float cj = (float)(N - 1 - 2 * j);  // scaling[j]

    const v4f* s4 = (const v4f*)(s + (size_t)b * N);
    const v4f* a4 = (const v4f*)(asum + (size_t)b * N);

    float v[32];
#pragma unroll
    for (int c = 0; c < 8; ++c) {
        v4f sv = s4[c * 64 + lane];
        v4f av = a4[c * 64 + lane];
        v[c * 4 + 0] = sv.x * cj - av.x;
        v[c * 4 + 1] = sv.y * cj - av.y;
        v[c * 4 + 2] = sv.z * cj - av.z;
        v[c * 4 + 3] = sv.w * cj - av.w;
    }

    // wave-level max reduction (width 64)
    float m = v[0];
#pragma unroll
    for (int i = 1; i < 32; ++i) m = fmaxf(m, v[i]);
#pragma unroll
    for (int off = 32; off >= 1; off >>= 1)
        m = fmaxf(m, __shfl_xor(m, off));

    // exp + wave-level sum reduction
    float sum = 0.0f;
#pragma unroll
    for (int i = 0; i < 32; ++i) {
        v[i] = __expf(v[i] - m);
        sum += v[i];
    }
#pragma unroll
    for (int off = 32; off >= 1; off >>= 1)
        sum += __shfl_xor(sum, off);

    const float r = 1.0f / sum;

    v4f* o4 = (v4f*)(out + ((size_t)b * N + j) * N);
#pragma unroll
    for (int c = 0; c < 8; ++c) {
        v4f o;
        o.x = v[c * 4 + 0] * r;
        o.y = v[c * 4 + 1] * r;
        o.z = v[c * 4 + 2] * r;
        o.w = v[c * 4 + 3] * r;
        __builtin_nontemporal_store(o, &o4[c * 64 + lane]);
    }
}

extern "C" void kernel_launch(void* const* d_in, const int* in_sizes, int n_in,
                              void* d_out, int out_size, void* d_ws, size_t ws_size,
                              hipStream_t stream) {
    const float* scores = (const float*)d_in[0];
    float* out = (float*)d_out;
    float* asum = (float*)d_ws;  // needs B*N*4 = 128 KB

    dim3 g1(N / 256, B);
    asum_kernel<<<g1, 256, 0, stream>>>(scores, asum);

    dim3 g2(N / 4, B);
    softmax_rows<<<g2, 256, 0, stream>>>(scores, asum, out);
}